// Round 1
// baseline (698.862 us; speedup 1.0000x reference)
//
#include <hip/hip_runtime.h>
#include <stdint.h>

// Problem constants (from reference)
#define N_TOK 8192
#define HDIM  1024
#define FDIM  4096
#define NEXP  8
#define MAXTILES 72   // 128-row tiles (fallback path): sum ceil(cnt/128) <= 64+7
#define MAXT256  40   // 256-row tiles: sum ceil(cnt/256) <= 32+7 = 39

typedef __attribute__((ext_vector_type(8))) __bf16 bf16x8;
typedef __attribute__((ext_vector_type(8))) unsigned short ushort8v;
typedef __attribute__((ext_vector_type(4))) unsigned short ushort4v;
typedef __attribute__((ext_vector_type(4))) float floatx4;

// f32 -> bf16 round-to-nearest-even
__device__ __forceinline__ unsigned short f2bf(float f) {
  union { float f; uint32_t u; } v; v.f = f;
  uint32_t u = v.u;
  return (unsigned short)((u + 0x7FFFu + ((u >> 16) & 1u)) >> 16);
}

// async global->LDS, 16B per lane. LDS dest is wave-uniform base + lane*16.
__device__ __forceinline__ void load_lds16(const void* g, void* l) {
  __builtin_amdgcn_global_load_lds(
      (const __attribute__((address_space(1))) void*)(uintptr_t)g,
      (__attribute__((address_space(3))) void*)(uint32_t)(uintptr_t)l,
      16, 0, 0);
}

// ws int layout: [0..7]=counts [8..15]=offsets [16..23]=cursors [24]=ntiles128
// [25]=ntiles256 [32..103]=tile128 list [104..143]=tile256 list (e<<16|mt).
// order[] at int offset 256 (N ints).
// Then (byte offsets): xs@65536 (16MB), h1 (64MB), w1b (64MB), w2b (64MB).

__global__ void k_count(const int* __restrict__ experts, int* __restrict__ meta) {
  int i = blockIdx.x * 256 + threadIdx.x;
  atomicAdd(&meta[experts[i]], 1);
}

__global__ void k_plan(int* __restrict__ meta) {
  if (threadIdx.x == 0) {
    int off = 0, nt = 0, nt2 = 0;
    for (int e = 0; e < NEXP; ++e) {
      int c = meta[e];
      meta[8 + e] = off;
      meta[16 + e] = off;
      int t = (c + 127) >> 7;
      for (int k = 0; k < t; ++k) meta[32 + nt++] = (e << 16) | k;
      int t2 = (c + 255) >> 8;
      for (int k = 0; k < t2; ++k) meta[104 + nt2++] = (e << 16) | k;
      off += c;
    }
    meta[24] = nt;
    meta[25] = nt2;
  }
}

__global__ void k_scatter(const int* __restrict__ experts, int* __restrict__ meta,
                          int* __restrict__ order) {
  int i = blockIdx.x * 256 + threadIdx.x;
  int e = experts[i];
  int pos = atomicAdd(&meta[16 + e], 1);
  order[pos] = i;
}

__global__ void k_pack(const float* __restrict__ x, const int* __restrict__ order,
                       unsigned short* __restrict__ xs) {
  int s = blockIdx.x;
  int i = order[s];
  int t = threadIdx.x;
  float4 v = *(const float4*)(x + (size_t)i * HDIM + t * 4);
  ushort4v u;
  u[0] = f2bf(v.x); u[1] = f2bf(v.y); u[2] = f2bf(v.z); u[3] = f2bf(v.w);
  *(ushort4v*)(xs + (size_t)s * HDIM + t * 4) = u;
}

// bulk f32 -> bf16 weight conversion: one float4 per thread
__global__ void k_cvt(const float* __restrict__ src, unsigned short* __restrict__ dst) {
  size_t i = ((size_t)blockIdx.x * 256 + threadIdx.x) * 4;
  float4 v = *(const float4*)(src + i);
  ushort4v u;
  u[0] = f2bf(v.x); u[1] = f2bf(v.y); u[2] = f2bf(v.z); u[3] = f2bf(v.w);
  *(ushort4v*)(dst + i) = u;
}

// ===================== Big-path GEMMs: 256-row tiles, BK=64, 8 waves =====================
//
// Structure (T3+T4 from the catalog, "counted vmcnt" pipeline):
//   prologue: STAGE(tile0 -> buf0)
//   for kt:   STAGE(tile kt+1 -> buf^1)          (8 resp. 6 global_load_lds / thread)
//             s_waitcnt vmcnt(ISSUES)            (oldest tile done; new stays in flight)
//             s_barrier; sched_barrier(0)
//             ds_read frags (swizzled) + MFMA    (compiler fine-schedules lgkmcnt)
//             s_barrier                          (reads done before buf reuse)
//
// LDS swizzle (T2, rule #21 both-sides): logical [row][64 bf16] with
//   byte ^= ((row&7)<<4).  global_load_lds writes LINEARLY, so the *global source*
//   of lane l is pre-permuted: col_shorts = ((l&7) ^ (l>>3)) << 3, row = w*8 + (l>>3)
//   (row&7 == l>>3, so this IS the involution).  ds_read applies the same XOR.
//   Verified spread: a wave's 64-lane ds_read_b128 hits every bank exactly 8 words
//   -> conflict-free (2 lanes/bank aliasing is free per m136).

#define VM_WAIT(n) asm volatile("s_waitcnt vmcnt(" #n ")" ::: "memory")

// ---- GEMM1 big: 256x256 tile, h1[s][f] = gelu(sum_h xs[s][h]*w1[e][f][h]) ----
// 8 waves as 2M x 4N; per-wave 128x64; acc[8][4]. K = 1024 -> 16 K-tiles.
__global__ __launch_bounds__(512, 1) void gemm1_big(
    const unsigned short* __restrict__ xs, const unsigned short* __restrict__ wb,
    unsigned short* __restrict__ h1, const int* __restrict__ meta) {
  __shared__ unsigned short As[2][256 * 64];   // 64KB
  __shared__ unsigned short Bs[2][256 * 64];   // 64KB

  int bx = blockIdx.z;
  if (bx >= meta[25]) return;
  int entry = meta[104 + bx];
  int e = entry >> 16, mt = entry & 0xffff;
  int row0 = meta[8 + e] + mt * 256;
  int rend = meta[8 + e] + meta[e];
  int fBase = blockIdx.x * 256;

  int tid = threadIdx.x;
  int w = tid >> 6, l = tid & 63;
  int r = l & 15, q = l >> 4;

  // staging geometry: per issue, wave w covers rows [n*64 + w*8, +8)
  int srow = w * 8 + (l >> 3);
  int scol = ((l & 7) ^ (l >> 3)) << 3;   // pre-swizzled source col (shorts)
  const unsigned short* aP[4];
  const unsigned short* bP[4];
#pragma unroll
  for (int n = 0; n < 4; ++n) {
    int ar = min(row0 + n * 64 + srow, N_TOK - 1);
    aP[n] = xs + (size_t)ar * HDIM + scol;
    int br = fBase + n * 64 + srow;
    bP[n] = wb + ((size_t)e * FDIM + br) * HDIM + scol;
  }

  floatx4 acc[8][4];
#pragma unroll
  for (int i = 0; i < 8; ++i)
#pragma unroll
    for (int j = 0; j < 4; ++j) acc[i][j] = (floatx4){0.f, 0.f, 0.f, 0.f};

  int mb = (w >> 2) * 128;   // wave row base
  int nb = (w & 3) * 64;     // wave col base

  // prologue stage of tile 0
  {
#pragma unroll
    for (int n = 0; n < 4; ++n) load_lds16(aP[n], &As[0][n * 4096 + w * 512]);
#pragma unroll
    for (int n = 0; n < 4; ++n) load_lds16(bP[n], &Bs[0][n * 4096 + w * 512]);
  }

  const int NT = HDIM / 64;  // 16
  for (int kt = 0; kt < NT; ++kt) {
    int cur = kt & 1;
    if (kt + 1 < NT) {
      int ko = (kt + 1) * 64;
      int nxt = cur ^ 1;
#pragma unroll
      for (int n = 0; n < 4; ++n) load_lds16(aP[n] + ko, &As[nxt][n * 4096 + w * 512]);
#pragma unroll
      for (int n = 0; n < 4; ++n) load_lds16(bP[n] + ko, &Bs[nxt][n * 4096 + w * 512]);
      VM_WAIT(8);            // tile kt staged; tile kt+1's 8 issues stay in flight
    } else {
      VM_WAIT(0);
    }
    __builtin_amdgcn_s_barrier();
    __builtin_amdgcn_sched_barrier(0);

#pragma unroll
    for (int kk = 0; kk < 2; ++kk) {
      bf16x8 av[8], bv[4];
#pragma unroll
      for (int i = 0; i < 8; ++i) {
        int row = mb + i * 16 + r;
        int col = (kk * 32 + q * 8) ^ ((r & 7) << 3);
        av[i] = __builtin_bit_cast(bf16x8, *(const ushort8v*)&As[cur][row * 64 + col]);
      }
#pragma unroll
      for (int j = 0; j < 4; ++j) {
        int row = nb + j * 16 + r;
        int col = (kk * 32 + q * 8) ^ ((r & 7) << 3);
        bv[j] = __builtin_bit_cast(bf16x8, *(const ushort8v*)&Bs[cur][row * 64 + col]);
      }
      __builtin_amdgcn_s_setprio(1);
#pragma unroll
      for (int i = 0; i < 8; ++i)
#pragma unroll
        for (int j = 0; j < 4; ++j)
          acc[i][j] = __builtin_amdgcn_mfma_f32_16x16x32_bf16(av[i], bv[j], acc[i][j], 0, 0, 0);
      __builtin_amdgcn_s_setprio(0);
    }
    __builtin_amdgcn_s_barrier();   // all reads of buf[cur] done before it is restaged
  }

  // epilogue: exact gelu, store bf16. D: row = q*4+reg, col = r.
#pragma unroll
  for (int i = 0; i < 8; ++i) {
    int mrow = row0 + mb + i * 16 + q * 4;
#pragma unroll
    for (int reg = 0; reg < 4; ++reg) {
      int s = mrow + reg;
      if (s < rend) {
        unsigned short* dst = h1 + (size_t)s * FDIM + fBase + nb + r;
#pragma unroll
        for (int j = 0; j < 4; ++j) {
          float v = acc[i][j][reg];
          float g = 0.5f * v * (1.0f + erff(v * 0.70710678118654752f));
          dst[j * 16] = f2bf(g);
        }
      }
    }
  }
}

// ---- GEMM2 big: 256x128 tile, K-split 2; fused gate+scatter+pair-reduce ----
// 8 waves as 4M x 2N; per-wave 64x64; acc[4][4]. K half = 2048 -> 32 K-tiles.
__global__ __launch_bounds__(512, 1) void gemm2_big(
    const unsigned short* __restrict__ h1, const unsigned short* __restrict__ wb,
    const float* __restrict__ gate, const int* __restrict__ new_index,
    float* __restrict__ out, const int* __restrict__ meta) {
  __shared__ unsigned short As[2][256 * 64];   // 64KB
  __shared__ unsigned short Bs[2][128 * 64];   // 32KB

  int bx = blockIdx.z;
  if (bx >= meta[25]) return;
  int entry = meta[104 + bx];
  int e = entry >> 16, mt = entry & 0xffff;
  int row0 = meta[8 + e] + mt * 256;
  int rend = meta[8 + e] + meta[e];
  int nBase = blockIdx.x * 128;
  int kStart = blockIdx.y * (FDIM / 2);
  const int* order = meta + 256;

  int tid = threadIdx.x;
  int w = tid >> 6, l = tid & 63;
  int r = l & 15, q = l >> 4;

  int srow = w * 8 + (l >> 3);
  int scol = ((l & 7) ^ (l >> 3)) << 3;
  const unsigned short* aP[4];
  const unsigned short* bP[2];
#pragma unroll
  for (int n = 0; n < 4; ++n) {
    int ar = min(row0 + n * 64 + srow, N_TOK - 1);
    aP[n] = h1 + (size_t)ar * FDIM + kStart + scol;
  }
#pragma unroll
  for (int n = 0; n < 2; ++n) {
    int br = nBase + n * 64 + srow;
    bP[n] = wb + ((size_t)e * HDIM + br) * FDIM + kStart + scol;
  }

  floatx4 acc[4][4];
#pragma unroll
  for (int i = 0; i < 4; ++i)
#pragma unroll
    for (int j = 0; j < 4; ++j) acc[i][j] = (floatx4){0.f, 0.f, 0.f, 0.f};

  int mb = (w >> 1) * 64;
  int nb = (w & 1) * 64;

  {
#pragma unroll
    for (int n = 0; n < 4; ++n) load_lds16(aP[n], &As[0][n * 4096 + w * 512]);
#pragma unroll
    for (int n = 0; n < 2; ++n) load_lds16(bP[n], &Bs[0][n * 4096 + w * 512]);
  }

  const int NT = (FDIM / 2) / 64;  // 32
  for (int kt = 0; kt < NT; ++kt) {
    int cur = kt & 1;
    if (kt + 1 < NT) {
      int ko = (kt + 1) * 64;
      int nxt = cur ^ 1;
#pragma unroll
      for (int n = 0; n < 4; ++n) load_lds16(aP[n] + ko, &As[nxt][n * 4096 + w * 512]);
#pragma unroll
      for (int n = 0; n < 2; ++n) load_lds16(bP[n] + ko, &Bs[nxt][n * 4096 + w * 512]);
      VM_WAIT(6);
    } else {
      VM_WAIT(0);
    }
    __builtin_amdgcn_s_barrier();
    __builtin_amdgcn_sched_barrier(0);

#pragma unroll
    for (int kk = 0; kk < 2; ++kk) {
      bf16x8 av[4], bv[4];
#pragma unroll
      for (int i = 0; i < 4; ++i) {
        int row = mb + i * 16 + r;
        int col = (kk * 32 + q * 8) ^ ((r & 7) << 3);
        av[i] = __builtin_bit_cast(bf16x8, *(const ushort8v*)&As[cur][row * 64 + col]);
      }
#pragma unroll
      for (int j = 0; j < 4; ++j) {
        int row = nb + j * 16 + r;
        int col = (kk * 32 + q * 8) ^ ((r & 7) << 3);
        bv[j] = __builtin_bit_cast(bf16x8, *(const ushort8v*)&Bs[cur][row * 64 + col]);
      }
      __builtin_amdgcn_s_setprio(1);
#pragma unroll
      for (int i = 0; i < 4; ++i)
#pragma unroll
        for (int j = 0; j < 4; ++j)
          acc[i][j] = __builtin_amdgcn_mfma_f32_16x16x32_bf16(av[i], bv[j], acc[i][j], 0, 0, 0);
      __builtin_amdgcn_s_setprio(0);
    }
    __builtin_amdgcn_s_barrier();
  }

  // epilogue: out[new_index[i]>>1][col] += gate[i]*y (atomic; 4 adds/element total)
#pragma unroll
  for (int i = 0; i < 4; ++i) {
    int mrow = row0 + mb + i * 16 + q * 4;
#pragma unroll
    for (int reg = 0; reg < 4; ++reg) {
      int s = mrow + reg;
      if (s < rend) {
        int itok = order[s];
        float gw = gate[itok];
        int jdx = new_index[itok];
        float* dst = out + (size_t)(jdx >> 1) * HDIM + nBase + nb + r;
#pragma unroll
        for (int j = 0; j < 4; ++j) atomicAdd(dst + j * 16, acc[i][j][reg] * gw);
      }
    }
  }
}

// ===================== Fallback (small workspace): original 128^2 kernels =====================

template <bool PRE>
__global__ __launch_bounds__(256) void gemm1_t(
    const unsigned short* __restrict__ xs, const void* __restrict__ w1v,
    unsigned short* __restrict__ h1, const int* __restrict__ meta) {
  __shared__ unsigned short As[128 * 32];
  __shared__ unsigned short Bs[128 * 32];

  int bx = blockIdx.z;
  if (bx >= meta[24]) return;
  int entry = meta[32 + bx];
  int e = entry >> 16, mt = entry & 0xffff;
  int row0 = meta[8 + e] + mt * 128;
  int rend = meta[8 + e] + meta[e];
  int fBase = blockIdx.x * 128;

  int tid = threadIdx.x;
  int w = tid >> 6, lane = tid & 63;
  int r = lane & 15, q = lane >> 4;
  int wm = (w >> 1) * 64, wn = (w & 1) * 64;

  int ar0 = (w * 16) + (lane >> 2);
  int s0 = min(row0 + ar0, N_TOK - 1);
  int s1 = min(row0 + 64 + ar0, N_TOK - 1);
  const unsigned short* ag0 = xs + (size_t)s0 * HDIM + (lane & 3) * 8;
  const unsigned short* ag1 = xs + (size_t)s1 * HDIM + (lane & 3) * 8;
  unsigned short* al0 = &As[(w * 16) * 32];
  unsigned short* al1 = &As[(64 + w * 16) * 32];

  const float* wbase = nullptr; int brow = 0, bkk = 0;
  brow = tid >> 1; bkk = (tid & 1) * 16;
  wbase = (const float*)w1v + ((size_t)e * FDIM + fBase + brow) * HDIM + bkk;

  floatx4 acc[4][4];
#pragma unroll
  for (int i = 0; i < 4; ++i)
#pragma unroll
    for (int j = 0; j < 4; ++j) acc[i][j] = (floatx4){0.f, 0.f, 0.f, 0.f};

  for (int k0 = 0; k0 < HDIM; k0 += 32) {
    __syncthreads();
    load_lds16(ag0 + k0, al0);
    load_lds16(ag1 + k0, al1);
    {
      const float* gb = wbase + k0;
      float4 f0 = *(const float4*)(gb);
      float4 f1 = *(const float4*)(gb + 4);
      float4 f2 = *(const float4*)(gb + 8);
      float4 f3 = *(const float4*)(gb + 12);
      ushort8v u0, u1;
      u0[0] = f2bf(f0.x); u0[1] = f2bf(f0.y); u0[2] = f2bf(f0.z); u0[3] = f2bf(f0.w);
      u0[4] = f2bf(f1.x); u0[5] = f2bf(f1.y); u0[6] = f2bf(f1.z); u0[7] = f2bf(f1.w);
      u1[0] = f2bf(f2.x); u1[1] = f2bf(f2.y); u1[2] = f2bf(f2.z); u1[3] = f2bf(f2.w);
      u1[4] = f2bf(f3.x); u1[5] = f2bf(f3.y); u1[6] = f2bf(f3.z); u1[7] = f2bf(f3.w);
      *(ushort8v*)&Bs[brow * 32 + bkk] = u0;
      *(ushort8v*)&Bs[brow * 32 + bkk + 8] = u1;
    }
    __syncthreads();

    bf16x8 av[4], bv[4];
#pragma unroll
    for (int i = 0; i < 4; ++i)
      av[i] = __builtin_bit_cast(bf16x8, *(const ushort8v*)&As[(wm + i * 16 + r) * 32 + q * 8]);
#pragma unroll
    for (int j = 0; j < 4; ++j)
      bv[j] = __builtin_bit_cast(bf16x8, *(const ushort8v*)&Bs[(wn + j * 16 + r) * 32 + q * 8]);
#pragma unroll
    for (int i = 0; i < 4; ++i)
#pragma unroll
      for (int j = 0; j < 4; ++j)
        acc[i][j] = __builtin_amdgcn_mfma_f32_16x16x32_bf16(av[i], bv[j], acc[i][j], 0, 0, 0);
  }

#pragma unroll
  for (int i = 0; i < 4; ++i) {
    int mrow = row0 + wm + i * 16 + q * 4;
#pragma unroll
    for (int reg = 0; reg < 4; ++reg) {
      int s = mrow + reg;
      if (s < rend) {
        unsigned short* dst = h1 + (size_t)s * FDIM + fBase + wn + r;
#pragma unroll
        for (int j = 0; j < 4; ++j) {
          float v = acc[i][j][reg];
          float g = 0.5f * v * (1.0f + erff(v * 0.70710678118654752f));
          dst[j * 16] = f2bf(g);
        }
      }
    }
  }
}

template <bool PRE>
__global__ __launch_bounds__(256) void gemm2_t(
    const unsigned short* __restrict__ h1, const void* __restrict__ w2v,
    const float* __restrict__ gate, const int* __restrict__ new_index,
    float* __restrict__ out, const int* __restrict__ meta) {
  __shared__ unsigned short As[128 * 32];
  __shared__ unsigned short Bs[128 * 32];

  int bx = blockIdx.z;
  if (bx >= meta[24]) return;
  int entry = meta[32 + bx];
  int e = entry >> 16, mt = entry & 0xffff;
  int row0 = meta[8 + e] + mt * 128;
  int rend = meta[8 + e] + meta[e];
  int nBase = blockIdx.x * 128;
  int kStart = blockIdx.y * (FDIM / 2);
  int kEnd = kStart + (FDIM / 2);
  const int* order = meta + 256;

  int tid = threadIdx.x;
  int w = tid >> 6, lane = tid & 63;
  int r = lane & 15, q = lane >> 4;
  int wm = (w >> 1) * 64, wn = (w & 1) * 64;

  int ar0 = (w * 16) + (lane >> 2);
  int s0 = min(row0 + ar0, N_TOK - 1);
  int s1 = min(row0 + 64 + ar0, N_TOK - 1);
  const unsigned short* ag0 = h1 + (size_t)s0 * FDIM + (lane & 3) * 8;
  const unsigned short* ag1 = h1 + (size_t)s1 * FDIM + (lane & 3) * 8;
  unsigned short* al0 = &As[(w * 16) * 32];
  unsigned short* al1 = &As[(64 + w * 16) * 32];

  const float* wbase = nullptr; int brow = 0, bkk = 0;
  brow = tid >> 1; bkk = (tid & 1) * 16;
  wbase = (const float*)w2v + ((size_t)e * HDIM + nBase + brow) * FDIM + bkk;

  floatx4 acc[4][4];
#pragma unroll
  for (int i = 0; i < 4; ++i)
#pragma unroll
    for (int j = 0; j < 4; ++j) acc[i][j] = (floatx4){0.f, 0.f, 0.f, 0.f};

  for (int k0 = kStart; k0 < kEnd; k0 += 32) {
    __syncthreads();
    load_lds16(ag0 + k0, al0);
    load_lds16(ag1 + k0, al1);
    {
      const float* gb = wbase + k0;
      float4 f0 = *(const float4*)(gb);
      float4 f1 = *(const float4*)(gb + 4);
      float4 f2 = *(const float4*)(gb + 8);
      float4 f3 = *(const float4*)(gb + 12);
      ushort8v u0, u1;
      u0[0] = f2bf(f0.x); u0[1] = f2bf(f0.y); u0[2] = f2bf(f0.z); u0[3] = f2bf(f0.w);
      u0[4] = f2bf(f1.x); u0[5] = f2bf(f1.y); u0[6] = f2bf(f1.z); u0[7] = f2bf(f1.w);
      u1[0] = f2bf(f2.x); u1[1] = f2bf(f2.y); u1[2] = f2bf(f2.z); u1[3] = f2bf(f2.w);
      u1[4] = f2bf(f3.x); u1[5] = f2bf(f3.y); u1[6] = f2bf(f3.z); u1[7] = f2bf(f3.w);
      *(ushort8v*)&Bs[brow * 32 + bkk] = u0;
      *(ushort8v*)&Bs[brow * 32 + bkk + 8] = u1;
    }
    __syncthreads();

    bf16x8 av[4], bv[4];
#pragma unroll
    for (int i = 0; i < 4; ++i)
      av[i] = __builtin_bit_cast(bf16x8, *(const ushort8v*)&As[(wm + i * 16 + r) * 32 + q * 8]);
#pragma unroll
    for (int j = 0; j < 4; ++j)
      bv[j] = __builtin_bit_cast(bf16x8, *(const ushort8v*)&Bs[(wn + j * 16 + r) * 32 + q * 8]);
#pragma unroll
    for (int i = 0; i < 4; ++i)
#pragma unroll
      for (int j = 0; j < 4; ++j)
        acc[i][j] = __builtin_amdgcn_mfma_f32_16x16x32_bf16(av[i], bv[j], acc[i][j], 0, 0, 0);
  }

#pragma unroll
  for (int i = 0; i < 4; ++i) {
    int mrow = row0 + wm + i * 16 + q * 4;
#pragma unroll
    for (int reg = 0; reg < 4; ++reg) {
      int s = mrow + reg;
      if (s < rend) {
        int itok = order[s];
        float gw = gate[itok];
        int jdx = new_index[itok];
        float* dst = out + (size_t)(jdx >> 1) * HDIM + nBase + wn + r;
#pragma unroll
        for (int j = 0; j < 4; ++j) atomicAdd(dst + j * 16, acc[i][j][reg] * gw);
      }
    }
  }
}

extern "C" void kernel_launch(void* const* d_in, const int* in_sizes, int n_in,
                              void* d_out, int out_size, void* d_ws, size_t ws_size,
                              hipStream_t stream) {
  const float* x        = (const float*)d_in[0];
  const float* gate     = (const float*)d_in[1];
  const int* experts    = (const int*)d_in[2];
  const int* new_index  = (const int*)d_in[3];
  const float* w1       = (const float*)d_in[4];
  const float* w2       = (const float*)d_in[5];
  float* out            = (float*)d_out;

  int* meta = (int*)d_ws;
  int* order = meta + 256;
  const size_t XS_OFF = 65536;
  const size_t XS_SZ  = (size_t)N_TOK * HDIM * 2;          // 16 MB
  const size_t H1_SZ  = (size_t)N_TOK * FDIM * 2;          // 64 MB
  const size_t W_SZ   = (size_t)NEXP * FDIM * HDIM * 2;    // 64 MB each
  unsigned short* xs  = (unsigned short*)((char*)d_ws + XS_OFF);
  unsigned short* h1  = (unsigned short*)((char*)d_ws + XS_OFF + XS_SZ);
  unsigned short* w1b = (unsigned short*)((char*)d_ws + XS_OFF + XS_SZ + H1_SZ);
  unsigned short* w2b = (unsigned short*)((char*)d_ws + XS_OFF + XS_SZ + H1_SZ + W_SZ);
  size_t need_small = XS_OFF + XS_SZ + H1_SZ;
  size_t need_big   = need_small + 2 * W_SZ;
  if (ws_size < need_small) return;
  bool big = ws_size >= need_big;

  hipMemsetAsync(d_ws, 0, 4096, stream);
  hipMemsetAsync(d_out, 0, (size_t)out_size * sizeof(float), stream);
  k_count<<<N_TOK / 256, 256, 0, stream>>>(experts, meta);
  k_plan<<<1, 64, 0, stream>>>(meta);
  k_scatter<<<N_TOK / 256, 256, 0, stream>>>(experts, meta, order);
  k_pack<<<N_TOK, 256, 0, stream>>>(x, order, xs);

  if (big) {
    int nblk = (int)((size_t)NEXP * FDIM * HDIM / 4 / 256);  // 32768
    k_cvt<<<nblk, 256, 0, stream>>>(w1, w1b);
    k_cvt<<<nblk, 256, 0, stream>>>(w2, w2b);
    gemm1_big<<<dim3(FDIM / 256, 1, MAXT256), 512, 0, stream>>>(xs, w1b, h1, meta);
    gemm2_big<<<dim3(HDIM / 128, 2, MAXT256), 512, 0, stream>>>(h1, w2b, gate, new_index, out, meta);
  } else {
    gemm1_t<false><<<dim3(FDIM / 128, 1, MAXTILES), 256, 0, stream>>>(xs, w1, h1, meta);
    gemm2_t<false><<<dim3(HDIM / 128, 2, MAXTILES), 256, 0, stream>>>(h1, w2, gate, new_index, out, meta);
  }
}

// Round 2
// 676.475 us; speedup vs baseline: 1.0331x; 1.0331x over previous
//
#include <hip/hip_runtime.h>
#include <stdint.h>

// Problem constants (from reference)
#define N_TOK 8192
#define HDIM  1024
#define FDIM  4096
#define NEXP  8
#define MAXTILES 72   // 128-row tiles (fallback path): sum ceil(cnt/128) <= 64+7
#define MAXT256  40   // 256-row tiles: sum ceil(cnt/256) <= 32+7 = 39

typedef __attribute__((ext_vector_type(8))) __bf16 bf16x8;
typedef __attribute__((ext_vector_type(8))) unsigned short ushort8v;
typedef __attribute__((ext_vector_type(4))) unsigned short ushort4v;
typedef __attribute__((ext_vector_type(4))) float floatx4;

// f32 -> bf16 round-to-nearest-even
__device__ __forceinline__ unsigned short f2bf(float f) {
  union { float f; uint32_t u; } v; v.f = f;
  uint32_t u = v.u;
  return (unsigned short)((u + 0x7FFFu + ((u >> 16) & 1u)) >> 16);
}

// async global->LDS, 16B per lane. LDS dest is wave-uniform base + lane*16.
__device__ __forceinline__ void load_lds16(const void* g, void* l) {
  __builtin_amdgcn_global_load_lds(
      (const __attribute__((address_space(1))) void*)(uintptr_t)g,
      (__attribute__((address_space(3))) void*)(uint32_t)(uintptr_t)l,
      16, 0, 0);
}

// ws int layout: [0..7]=counts [8..15]=offsets [16..23]=cursors [24]=ntiles128
// [25]=ntiles256 [32..103]=tile128 list [104..143]=tile256 list (e<<16|mt).
// order[] at int offset 256 (N ints).
// Then (byte offsets): xs@65536 (16MB), h1 (64MB), w1b (64MB), w2b (64MB).

__global__ void k_count(const int* __restrict__ experts, int* __restrict__ meta) {
  int i = blockIdx.x * 256 + threadIdx.x;
  atomicAdd(&meta[experts[i]], 1);
}

__global__ void k_plan(int* __restrict__ meta) {
  if (threadIdx.x == 0) {
    int off = 0, nt = 0, nt2 = 0;
    for (int e = 0; e < NEXP; ++e) {
      int c = meta[e];
      meta[8 + e] = off;
      meta[16 + e] = off;
      int t = (c + 127) >> 7;
      for (int k = 0; k < t; ++k) meta[32 + nt++] = (e << 16) | k;
      int t2 = (c + 255) >> 8;
      for (int k = 0; k < t2; ++k) meta[104 + nt2++] = (e << 16) | k;
      off += c;
    }
    meta[24] = nt;
    meta[25] = nt2;
  }
}

__global__ void k_scatter(const int* __restrict__ experts, int* __restrict__ meta,
                          int* __restrict__ order) {
  int i = blockIdx.x * 256 + threadIdx.x;
  int e = experts[i];
  int pos = atomicAdd(&meta[16 + e], 1);
  order[pos] = i;
}

__global__ void k_pack(const float* __restrict__ x, const int* __restrict__ order,
                       unsigned short* __restrict__ xs) {
  int s = blockIdx.x;
  int i = order[s];
  int t = threadIdx.x;
  float4 v = *(const float4*)(x + (size_t)i * HDIM + t * 4);
  ushort4v u;
  u[0] = f2bf(v.x); u[1] = f2bf(v.y); u[2] = f2bf(v.z); u[3] = f2bf(v.w);
  *(ushort4v*)(xs + (size_t)s * HDIM + t * 4) = u;
}

// bulk f32 -> bf16 weight conversion: one float4 per thread
__global__ void k_cvt(const float* __restrict__ src, unsigned short* __restrict__ dst) {
  size_t i = ((size_t)blockIdx.x * 256 + threadIdx.x) * 4;
  float4 v = *(const float4*)(src + i);
  ushort4v u;
  u[0] = f2bf(v.x); u[1] = f2bf(v.y); u[2] = f2bf(v.z); u[3] = f2bf(v.w);
  *(ushort4v*)(dst + i) = u;
}

// ===================== Unified big-path GEMM: 256x128 tile, BK=64 ======================
//
// Pipeline (this round's change): TRIPLE-buffered LDS, lookahead = 2 K-tiles,
// ONE barrier per K-tile, stage-issue AFTER the barrier.
//
//   prologue: stage(t0->buf0); stage(t1->buf1)
//   tile kt : VM_WAIT(6)      // kt+1's 6 loads stay in flight; kt's done
//             s_barrier; sched_barrier(0)
//             stage(t_{kt+2} -> buf[(kt+2)%3])   // post-barrier => clobber-safe:
//                 // region (kt+2)%3 == (kt-1)%3 was last READ in tile kt-1's body;
//                 // each wave's ds_reads complete (lgkmcnt) before its kt-1 MFMAs,
//                 // hence before it arrives at THIS barrier. Writer issues after.
//             ds_read frags (swizzled) + MFMA (setprio around cluster)
//             // no trailing barrier needed: next write to buf[kt%3] is issued
//             // after the barrier at top of kt+1, which all readers passed.
//   tail    : kt==NT-1 uses VM_WAIT(0) (no newer loads exist to count against).
//
// Per-tile slack for the 6 in-flight loads = two full compute phases (~2500+ cyc)
// vs ~1 phase in round-1. LDS 144KB => 1 block/CU (as before), VGPR ~90.
//
// LDS swizzle unchanged from round-1 (refcheck-passed, bank-conflict 0):
//   source pre-permute: scol = ((l&7)^(l>>3))<<3 ; read col ^= ((r&7)<<3).
//
// Template: K_TOTAL = row stride of A and B (=K dim total), NT = K-tiles this block
// (kStart = blockIdx.y * NT*64 for K-split), EPI: 0 = gelu->h1 store, 1 = gate+
// scatter+pair-reduce atomic into out.

#define VM_WAIT(n) asm volatile("s_waitcnt vmcnt(" #n ")" ::: "memory")

template <int K_TOTAL, int NT, int EPI>
__global__ __launch_bounds__(512, 1) void gemm_big(
    const unsigned short* __restrict__ A, const unsigned short* __restrict__ B,
    unsigned short* __restrict__ h1out, const float* __restrict__ gate,
    const int* __restrict__ new_index, float* __restrict__ out,
    const int* __restrict__ meta) {
  __shared__ unsigned short As[3][256 * 64];   // 96KB
  __shared__ unsigned short Bs[3][128 * 64];   // 48KB

  int bx = blockIdx.z;
  if (bx >= meta[25]) return;
  int entry = meta[104 + bx];
  int e = entry >> 16, mt = entry & 0xffff;
  int row0 = meta[8 + e] + mt * 256;
  int rend = meta[8 + e] + meta[e];
  int nBase = blockIdx.x * 128;
  int kStart = blockIdx.y * (NT * 64);

  int tid = threadIdx.x;
  int w = tid >> 6, l = tid & 63;
  int r = l & 15, q = l >> 4;

  // staging geometry: per issue, wave w covers rows [n*64 + w*8, +8)
  int srow = w * 8 + (l >> 3);
  int scol = ((l & 7) ^ (l >> 3)) << 3;   // pre-swizzled source col (shorts)
  const unsigned short* aP[4];
  const unsigned short* bP[2];
#pragma unroll
  for (int n = 0; n < 4; ++n) {
    int ar = min(row0 + n * 64 + srow, N_TOK - 1);
    aP[n] = A + (size_t)ar * K_TOTAL + kStart + scol;
  }
#pragma unroll
  for (int n = 0; n < 2; ++n) {
    int br = nBase + n * 64 + srow;
    bP[n] = B + (size_t)e * 4194304 + (size_t)br * K_TOTAL + kStart + scol;
  }

  floatx4 acc[4][4];
#pragma unroll
  for (int i = 0; i < 4; ++i)
#pragma unroll
    for (int j = 0; j < 4; ++j) acc[i][j] = (floatx4){0.f, 0.f, 0.f, 0.f};

  int mb = (w >> 1) * 64;   // wave row base (4M)
  int nb = (w & 1) * 64;    // wave col base (2N)

  // prologue: stage tiles 0 and 1
#pragma unroll
  for (int n = 0; n < 4; ++n) load_lds16(aP[n], &As[0][n * 4096 + w * 512]);
#pragma unroll
  for (int n = 0; n < 2; ++n) load_lds16(bP[n], &Bs[0][n * 4096 + w * 512]);
#pragma unroll
  for (int n = 0; n < 4; ++n) load_lds16(aP[n] + 64, &As[1][n * 4096 + w * 512]);
#pragma unroll
  for (int n = 0; n < 2; ++n) load_lds16(bP[n] + 64, &Bs[1][n * 4096 + w * 512]);

  int cur = 0;
  for (int kt = 0; kt < NT; ++kt) {
    if (kt == NT - 1) { VM_WAIT(0); } else { VM_WAIT(6); }
    __builtin_amdgcn_s_barrier();
    __builtin_amdgcn_sched_barrier(0);

    if (kt + 2 < NT) {
      int stg = cur + 2; if (stg >= 3) stg -= 3;
      int ko = (kt + 2) * 64;
#pragma unroll
      for (int n = 0; n < 4; ++n) load_lds16(aP[n] + ko, &As[stg][n * 4096 + w * 512]);
#pragma unroll
      for (int n = 0; n < 2; ++n) load_lds16(bP[n] + ko, &Bs[stg][n * 4096 + w * 512]);
    }

#pragma unroll
    for (int kk = 0; kk < 2; ++kk) {
      bf16x8 av[4], bv[4];
#pragma unroll
      for (int i = 0; i < 4; ++i) {
        int row = mb + i * 16 + r;
        int col = (kk * 32 + q * 8) ^ ((r & 7) << 3);
        av[i] = __builtin_bit_cast(bf16x8, *(const ushort8v*)&As[cur][row * 64 + col]);
      }
#pragma unroll
      for (int j = 0; j < 4; ++j) {
        int row = nb + j * 16 + r;
        int col = (kk * 32 + q * 8) ^ ((r & 7) << 3);
        bv[j] = __builtin_bit_cast(bf16x8, *(const ushort8v*)&Bs[cur][row * 64 + col]);
      }
      __builtin_amdgcn_s_setprio(1);
#pragma unroll
      for (int i = 0; i < 4; ++i)
#pragma unroll
        for (int j = 0; j < 4; ++j)
          acc[i][j] = __builtin_amdgcn_mfma_f32_16x16x32_bf16(av[i], bv[j], acc[i][j], 0, 0, 0);
      __builtin_amdgcn_s_setprio(0);
    }

    ++cur; if (cur >= 3) cur = 0;
  }

  if constexpr (EPI == 0) {
    // gelu, store bf16 to h1. D: row = q*4+reg, col = r.
#pragma unroll
    for (int i = 0; i < 4; ++i) {
      int mrow = row0 + mb + i * 16 + q * 4;
#pragma unroll
      for (int reg = 0; reg < 4; ++reg) {
        int s = mrow + reg;
        if (s < rend) {
          unsigned short* dst = h1out + (size_t)s * FDIM + nBase + nb + r;
#pragma unroll
          for (int j = 0; j < 4; ++j) {
            float v = acc[i][j][reg];
            float g = 0.5f * v * (1.0f + erff(v * 0.70710678118654752f));
            dst[j * 16] = f2bf(g);
          }
        }
      }
    }
  } else {
    // out[new_index[i]>>1][col] += gate[i]*y (atomic; pair-reduce + K-split)
    const int* order = meta + 256;
#pragma unroll
    for (int i = 0; i < 4; ++i) {
      int mrow = row0 + mb + i * 16 + q * 4;
#pragma unroll
      for (int reg = 0; reg < 4; ++reg) {
        int s = mrow + reg;
        if (s < rend) {
          int itok = order[s];
          float gw = gate[itok];
          int jdx = new_index[itok];
          float* dst = out + (size_t)(jdx >> 1) * HDIM + nBase + nb + r;
#pragma unroll
          for (int j = 0; j < 4; ++j) atomicAdd(dst + j * 16, acc[i][j][reg] * gw);
        }
      }
    }
  }
}

// ===================== Fallback (small workspace): original 128^2 kernels =====================

template <bool PRE>
__global__ __launch_bounds__(256) void gemm1_t(
    const unsigned short* __restrict__ xs, const void* __restrict__ w1v,
    unsigned short* __restrict__ h1, const int* __restrict__ meta) {
  __shared__ unsigned short As[128 * 32];
  __shared__ unsigned short Bs[128 * 32];

  int bx = blockIdx.z;
  if (bx >= meta[24]) return;
  int entry = meta[32 + bx];
  int e = entry >> 16, mt = entry & 0xffff;
  int row0 = meta[8 + e] + mt * 128;
  int rend = meta[8 + e] + meta[e];
  int fBase = blockIdx.x * 128;

  int tid = threadIdx.x;
  int w = tid >> 6, lane = tid & 63;
  int r = lane & 15, q = lane >> 4;
  int wm = (w >> 1) * 64, wn = (w & 1) * 64;

  int ar0 = (w * 16) + (lane >> 2);
  int s0 = min(row0 + ar0, N_TOK - 1);
  int s1 = min(row0 + 64 + ar0, N_TOK - 1);
  const unsigned short* ag0 = xs + (size_t)s0 * HDIM + (lane & 3) * 8;
  const unsigned short* ag1 = xs + (size_t)s1 * HDIM + (lane & 3) * 8;
  unsigned short* al0 = &As[(w * 16) * 32];
  unsigned short* al1 = &As[(64 + w * 16) * 32];

  const float* wbase = nullptr; int brow = 0, bkk = 0;
  brow = tid >> 1; bkk = (tid & 1) * 16;
  wbase = (const float*)w1v + ((size_t)e * FDIM + fBase + brow) * HDIM + bkk;

  floatx4 acc[4][4];
#pragma unroll
  for (int i = 0; i < 4; ++i)
#pragma unroll
    for (int j = 0; j < 4; ++j) acc[i][j] = (floatx4){0.f, 0.f, 0.f, 0.f};

  for (int k0 = 0; k0 < HDIM; k0 += 32) {
    __syncthreads();
    load_lds16(ag0 + k0, al0);
    load_lds16(ag1 + k0, al1);
    {
      const float* gb = wbase + k0;
      float4 f0 = *(const float4*)(gb);
      float4 f1 = *(const float4*)(gb + 4);
      float4 f2 = *(const float4*)(gb + 8);
      float4 f3 = *(const float4*)(gb + 12);
      ushort8v u0, u1;
      u0[0] = f2bf(f0.x); u0[1] = f2bf(f0.y); u0[2] = f2bf(f0.z); u0[3] = f2bf(f0.w);
      u0[4] = f2bf(f1.x); u0[5] = f2bf(f1.y); u0[6] = f2bf(f1.z); u0[7] = f2bf(f1.w);
      u1[0] = f2bf(f2.x); u1[1] = f2bf(f2.y); u1[2] = f2bf(f2.z); u1[3] = f2bf(f2.w);
      u1[4] = f2bf(f3.x); u1[5] = f2bf(f3.y); u1[6] = f2bf(f3.z); u1[7] = f2bf(f3.w);
      *(ushort8v*)&Bs[brow * 32 + bkk] = u0;
      *(ushort8v*)&Bs[brow * 32 + bkk + 8] = u1;
    }
    __syncthreads();

    bf16x8 av[4], bv[4];
#pragma unroll
    for (int i = 0; i < 4; ++i)
      av[i] = __builtin_bit_cast(bf16x8, *(const ushort8v*)&As[(wm + i * 16 + r) * 32 + q * 8]);
#pragma unroll
    for (int j = 0; j < 4; ++j)
      bv[j] = __builtin_bit_cast(bf16x8, *(const ushort8v*)&Bs[(wn + j * 16 + r) * 32 + q * 8]);
#pragma unroll
    for (int i = 0; i < 4; ++i)
#pragma unroll
      for (int j = 0; j < 4; ++j)
        acc[i][j] = __builtin_amdgcn_mfma_f32_16x16x32_bf16(av[i], bv[j], acc[i][j], 0, 0, 0);
  }

#pragma unroll
  for (int i = 0; i < 4; ++i) {
    int mrow = row0 + wm + i * 16 + q * 4;
#pragma unroll
    for (int reg = 0; reg < 4; ++reg) {
      int s = mrow + reg;
      if (s < rend) {
        unsigned short* dst = h1 + (size_t)s * FDIM + fBase + wn + r;
#pragma unroll
        for (int j = 0; j < 4; ++j) {
          float v = acc[i][j][reg];
          float g = 0.5f * v * (1.0f + erff(v * 0.70710678118654752f));
          dst[j * 16] = f2bf(g);
        }
      }
    }
  }
}

template <bool PRE>
__global__ __launch_bounds__(256) void gemm2_t(
    const unsigned short* __restrict__ h1, const void* __restrict__ w2v,
    const float* __restrict__ gate, const int* __restrict__ new_index,
    float* __restrict__ out, const int* __restrict__ meta) {
  __shared__ unsigned short As[128 * 32];
  __shared__ unsigned short Bs[128 * 32];

  int bx = blockIdx.z;
  if (bx >= meta[24]) return;
  int entry = meta[32 + bx];
  int e = entry >> 16, mt = entry & 0xffff;
  int row0 = meta[8 + e] + mt * 128;
  int rend = meta[8 + e] + meta[e];
  int nBase = blockIdx.x * 128;
  int kStart = blockIdx.y * (FDIM / 2);
  int kEnd = kStart + (FDIM / 2);
  const int* order = meta + 256;

  int tid = threadIdx.x;
  int w = tid >> 6, lane = tid & 63;
  int r = lane & 15, q = lane >> 4;
  int wm = (w >> 1) * 64, wn = (w & 1) * 64;

  int ar0 = (w * 16) + (lane >> 2);
  int s0 = min(row0 + ar0, N_TOK - 1);
  int s1 = min(row0 + 64 + ar0, N_TOK - 1);
  const unsigned short* ag0 = h1 + (size_t)s0 * FDIM + (lane & 3) * 8;
  const unsigned short* ag1 = h1 + (size_t)s1 * FDIM + (lane & 3) * 8;
  unsigned short* al0 = &As[(w * 16) * 32];
  unsigned short* al1 = &As[(64 + w * 16) * 32];

  const float* wbase = nullptr; int brow = 0, bkk = 0;
  brow = tid >> 1; bkk = (tid & 1) * 16;
  wbase = (const float*)w2v + ((size_t)e * HDIM + nBase + brow) * FDIM + bkk;

  floatx4 acc[4][4];
#pragma unroll
  for (int i = 0; i < 4; ++i)
#pragma unroll
    for (int j = 0; j < 4; ++j) acc[i][j] = (floatx4){0.f, 0.f, 0.f, 0.f};

  for (int k0 = kStart; k0 < kEnd; k0 += 32) {
    __syncthreads();
    load_lds16(ag0 + k0, al0);
    load_lds16(ag1 + k0, al1);
    {
      const float* gb = wbase + k0;
      float4 f0 = *(const float4*)(gb);
      float4 f1 = *(const float4*)(gb + 4);
      float4 f2 = *(const float4*)(gb + 8);
      float4 f3 = *(const float4*)(gb + 12);
      ushort8v u0, u1;
      u0[0] = f2bf(f0.x); u0[1] = f2bf(f0.y); u0[2] = f2bf(f0.z); u0[3] = f2bf(f0.w);
      u0[4] = f2bf(f1.x); u0[5] = f2bf(f1.y); u0[6] = f2bf(f1.z); u0[7] = f2bf(f1.w);
      u1[0] = f2bf(f2.x); u1[1] = f2bf(f2.y); u1[2] = f2bf(f2.z); u1[3] = f2bf(f2.w);
      u1[4] = f2bf(f3.x); u1[5] = f2bf(f3.y); u1[6] = f2bf(f3.z); u1[7] = f2bf(f3.w);
      *(ushort8v*)&Bs[brow * 32 + bkk] = u0;
      *(ushort8v*)&Bs[brow * 32 + bkk + 8] = u1;
    }
    __syncthreads();

    bf16x8 av[4], bv[4];
#pragma unroll
    for (int i = 0; i < 4; ++i)
      av[i] = __builtin_bit_cast(bf16x8, *(const ushort8v*)&As[(wm + i * 16 + r) * 32 + q * 8]);
#pragma unroll
    for (int j = 0; j < 4; ++j)
      bv[j] = __builtin_bit_cast(bf16x8, *(const ushort8v*)&Bs[(wn + j * 16 + r) * 32 + q * 8]);
#pragma unroll
    for (int i = 0; i < 4; ++i)
#pragma unroll
      for (int j = 0; j < 4; ++j)
        acc[i][j] = __builtin_amdgcn_mfma_f32_16x16x32_bf16(av[i], bv[j], acc[i][j], 0, 0, 0);
  }

#pragma unroll
  for (int i = 0; i < 4; ++i) {
    int mrow = row0 + wm + i * 16 + q * 4;
#pragma unroll
    for (int reg = 0; reg < 4; ++reg) {
      int s = mrow + reg;
      if (s < rend) {
        int itok = order[s];
        float gw = gate[itok];
        int jdx = new_index[itok];
        float* dst = out + (size_t)(jdx >> 1) * HDIM + nBase + wn + r;
#pragma unroll
        for (int j = 0; j < 4; ++j) atomicAdd(dst + j * 16, acc[i][j][reg] * gw);
      }
    }
  }
}

extern "C" void kernel_launch(void* const* d_in, const int* in_sizes, int n_in,
                              void* d_out, int out_size, void* d_ws, size_t ws_size,
                              hipStream_t stream) {
  const float* x        = (const float*)d_in[0];
  const float* gate     = (const float*)d_in[1];
  const int* experts    = (const int*)d_in[2];
  const int* new_index  = (const int*)d_in[3];
  const float* w1       = (const float*)d_in[4];
  const float* w2       = (const float*)d_in[5];
  float* out            = (float*)d_out;

  int* meta = (int*)d_ws;
  int* order = meta + 256;
  const size_t XS_OFF = 65536;
  const size_t XS_SZ  = (size_t)N_TOK * HDIM * 2;          // 16 MB
  const size_t H1_SZ  = (size_t)N_TOK * FDIM * 2;          // 64 MB
  const size_t W_SZ   = (size_t)NEXP * FDIM * HDIM * 2;    // 64 MB each
  unsigned short* xs  = (unsigned short*)((char*)d_ws + XS_OFF);
  unsigned short* h1  = (unsigned short*)((char*)d_ws + XS_OFF + XS_SZ);
  unsigned short* w1b = (unsigned short*)((char*)d_ws + XS_OFF + XS_SZ + H1_SZ);
  unsigned short* w2b = (unsigned short*)((char*)d_ws + XS_OFF + XS_SZ + H1_SZ + W_SZ);
  size_t need_small = XS_OFF + XS_SZ + H1_SZ;
  size_t need_big   = need_small + 2 * W_SZ;
  if (ws_size < need_small) return;
  bool big = ws_size >= need_big;

  hipMemsetAsync(d_ws, 0, 4096, stream);
  hipMemsetAsync(d_out, 0, (size_t)out_size * sizeof(float), stream);
  k_count<<<N_TOK / 256, 256, 0, stream>>>(experts, meta);
  k_plan<<<1, 64, 0, stream>>>(meta);
  k_scatter<<<N_TOK / 256, 256, 0, stream>>>(experts, meta, order);
  k_pack<<<N_TOK, 256, 0, stream>>>(x, order, xs);

  if (big) {
    int nblk = (int)((size_t)NEXP * FDIM * HDIM / 4 / 256);  // 32768
    k_cvt<<<nblk, 256, 0, stream>>>(w1, w1b);
    k_cvt<<<nblk, 256, 0, stream>>>(w2, w2b);
    // gemm1: M=tokens, N=FDIM (x=32 tiles of 128), K=1024 (NT=16, no K-split)
    gemm_big<HDIM, 16, 0><<<dim3(FDIM / 128, 1, MAXT256), 512, 0, stream>>>(
        xs, w1b, h1, nullptr, nullptr, nullptr, meta);
    // gemm2: M=tokens, N=HDIM (x=8 tiles of 128), K=4096 split 2 (NT=32)
    gemm_big<FDIM, 32, 1><<<dim3(HDIM / 128, 2, MAXT256), 512, 0, stream>>>(
        h1, w2b, nullptr, gate, new_index, out, meta);
  } else {
    gemm1_t<false><<<dim3(FDIM / 128, 1, MAXTILES), 256, 0, stream>>>(xs, w1, h1, meta);
    gemm2_t<false><<<dim3(HDIM / 128, 2, MAXTILES), 256, 0, stream>>>(h1, w2, gate, new_index, out, meta);
  }
}

// Round 3
// 583.391 us; speedup vs baseline: 1.1979x; 1.1596x over previous
//
#include <hip/hip_runtime.h>
#include <stdint.h>

// Problem constants (from reference)
#define N_TOK 8192
#define HDIM  1024
#define FDIM  4096
#define NEXP  8
#define MAXTILES 72   // 128-row tiles: sum ceil(cnt/128) <= 64+7
#define MAXT256  40   // 256-row tiles: sum ceil(cnt/256) <= 32+7 = 39

typedef __attribute__((ext_vector_type(8))) __bf16 bf16x8;
typedef __attribute__((ext_vector_type(8))) unsigned short ushort8v;
typedef __attribute__((ext_vector_type(4))) unsigned short ushort4v;
typedef __attribute__((ext_vector_type(4))) float floatx4;

// f32 -> bf16 round-to-nearest-even
__device__ __forceinline__ unsigned short f2bf(float f) {
  union { float f; uint32_t u; } v; v.f = f;
  uint32_t u = v.u;
  return (unsigned short)((u + 0x7FFFu + ((u >> 16) & 1u)) >> 16);
}

// async global->LDS, 16B per lane. LDS dest is wave-uniform base + lane*16.
__device__ __forceinline__ void load_lds16(const void* g, void* l) {
  __builtin_amdgcn_global_load_lds(
      (const __attribute__((address_space(1))) void*)(uintptr_t)g,
      (__attribute__((address_space(3))) void*)(uint32_t)(uintptr_t)l,
      16, 0, 0);
}

// ws int layout: [0..7]=counts [8..15]=offsets [24]=ntiles128 [25]=ntiles256
// [32..103]=tile128 list [104..143]=tile256 list (e<<16|mt).
// order[] at int offset 256 (N ints).
// Then (byte offsets): xs@65536 (16MB), h1 (64MB), w1b (64MB), w2b (64MB).

// Fused count + plan + scatter (single block; removes 2 dispatch gaps and the
// serial-latency k_plan kernel). LDS atomics over 8 counters.
__global__ __launch_bounds__(1024) void k_prep(const int* __restrict__ experts,
                                               int* __restrict__ meta,
                                               int* __restrict__ order) {
  __shared__ int cnt[NEXP];
  __shared__ int base[NEXP];
  int tid = threadIdx.x;
  if (tid < NEXP) cnt[tid] = 0;
  __syncthreads();
  int eloc[8];
#pragma unroll
  for (int k = 0; k < 8; ++k) {
    int e = experts[tid + k * 1024];
    eloc[k] = e;
    atomicAdd(&cnt[e], 1);
  }
  __syncthreads();
  if (tid == 0) {
    int off = 0, nt = 0, nt2 = 0;
    for (int e = 0; e < NEXP; ++e) {
      int c = cnt[e];
      meta[e] = c;
      meta[8 + e] = off;
      base[e] = off;
      int t = (c + 127) >> 7;
      for (int k = 0; k < t; ++k) meta[32 + nt++] = (e << 16) | k;
      int t2 = (c + 255) >> 8;
      for (int k = 0; k < t2; ++k) meta[104 + nt2++] = (e << 16) | k;
      off += c;
    }
    meta[24] = nt;
    meta[25] = nt2;
  }
  __syncthreads();
  if (tid < NEXP) cnt[tid] = base[tid];   // reuse as cursors
  __syncthreads();
#pragma unroll
  for (int k = 0; k < 8; ++k) {
    int pos = atomicAdd(&cnt[eloc[k]], 1);
    order[pos] = tid + k * 1024;
  }
}

__global__ void k_pack(const float* __restrict__ x, const int* __restrict__ order,
                       unsigned short* __restrict__ xs) {
  int s = blockIdx.x;
  int i = order[s];
  int t = threadIdx.x;
  float4 v = *(const float4*)(x + (size_t)i * HDIM + t * 4);
  ushort4v u;
  u[0] = f2bf(v.x); u[1] = f2bf(v.y); u[2] = f2bf(v.z); u[3] = f2bf(v.w);
  *(ushort4v*)(xs + (size_t)s * HDIM + t * 4) = u;
}

// bulk f32 -> bf16 weight conversion: one float4 per thread
__global__ void k_cvt(const float* __restrict__ src, unsigned short* __restrict__ dst) {
  size_t i = ((size_t)blockIdx.x * 256 + threadIdx.x) * 4;
  float4 v = *(const float4*)(src + i);
  ushort4v u;
  u[0] = f2bf(v.x); u[1] = f2bf(v.y); u[2] = f2bf(v.z); u[3] = f2bf(v.w);
  *(ushort4v*)(dst + i) = u;
}

// ===================== Unified big-path GEMM: 256x128 tile, BK=32 ======================
//
// ROUND-3 CHANGE: BK 64->32 shrinks LDS 144KB -> 72KB  =>  2 blocks/CU.
// Cross-block TLP is the latency-hiding mechanism (m114): when one block sits at
// its barrier/vmcnt, the co-resident block's waves feed MFMA + VMEM pipes.
// Pipeline otherwise as round-2: TRIPLE-buffered LDS, lookahead-2 K-tiles,
// ONE barrier per K-tile, stage-issue AFTER the barrier (clobber-safe: the
// region being restaged was last read one full tile ago; those ds_reads
// completed before their MFMAs, hence before this barrier).
//
// Staging: 3 issues/thread/tile (A: 2, B: 1), each issue = 16 rows x 32 cols.
//   lane l covers row (l>>2), col-slot (l&3); source col pre-swizzled by the
//   involution slot^(row&3):  scol = ((l&3) ^ ((l>>2)&3)) << 3 shorts.
// ds_read applies the same XOR: col = (q ^ (r&3)) * 8 shorts.
//   Bank check: byte = row*64 + c*16, bank_start = 16*(row&1)+4c -> 8 distinct
//   4-bank slots, 8 lanes each = 2 lanes/bank => conflict-free (m136).
// vmcnt: steady VM_WAIT(3) (= tile kt+1's 3 issues stay in flight), 0 at tail.

#define VM_WAIT(n) asm volatile("s_waitcnt vmcnt(" #n ")" ::: "memory")

template <int K_TOTAL, int NT, int EPI>
__global__ __launch_bounds__(512, 4) void gemm_big(
    const unsigned short* __restrict__ A, const unsigned short* __restrict__ B,
    unsigned short* __restrict__ h1out, const float* __restrict__ gate,
    const int* __restrict__ new_index, float* __restrict__ out,
    const int* __restrict__ meta) {
  __shared__ unsigned short As[3][256 * 32];   // 48KB
  __shared__ unsigned short Bs[3][128 * 32];   // 24KB

  int bx = blockIdx.z;
  if (bx >= meta[25]) return;
  int entry = meta[104 + bx];
  int e = entry >> 16, mt = entry & 0xffff;
  int row0 = meta[8 + e] + mt * 256;
  int rend = meta[8 + e] + meta[e];
  int nBase = blockIdx.x * 128;
  int kStart = blockIdx.y * (NT * 32);

  int tid = threadIdx.x;
  int w = tid >> 6, l = tid & 63;
  int r = l & 15, q = l >> 4;

  // staging geometry: each issue covers 16 rows x 32 cols; lane l -> row l>>2.
  int srow = w * 16 + (l >> 2);
  int scol = ((l & 3) ^ ((l >> 2) & 3)) << 3;   // pre-swizzled source col (shorts)
  const unsigned short* aP[2];
  const unsigned short* bP;
#pragma unroll
  for (int n = 0; n < 2; ++n) {
    int ar = min(row0 + n * 128 + srow, N_TOK - 1);
    aP[n] = A + (size_t)ar * K_TOTAL + kStart + scol;
  }
  {
    int br = nBase + srow;
    bP = B + (size_t)e * 4194304 + (size_t)br * K_TOTAL + kStart + scol;
  }

  floatx4 acc[4][4];
#pragma unroll
  for (int i = 0; i < 4; ++i)
#pragma unroll
    for (int j = 0; j < 4; ++j) acc[i][j] = (floatx4){0.f, 0.f, 0.f, 0.f};

  int mb = (w >> 1) * 64;   // wave row base (4M)
  int nb = (w & 1) * 64;    // wave col base (2N)

  // prologue: stage tiles 0 and 1
#pragma unroll
  for (int n = 0; n < 2; ++n) load_lds16(aP[n], &As[0][(n * 128 + w * 16) * 32]);
  load_lds16(bP, &Bs[0][(w * 16) * 32]);
#pragma unroll
  for (int n = 0; n < 2; ++n) load_lds16(aP[n] + 32, &As[1][(n * 128 + w * 16) * 32]);
  load_lds16(bP + 32, &Bs[1][(w * 16) * 32]);

  int cur = 0;
  for (int kt = 0; kt < NT; ++kt) {
    if (kt == NT - 1) { VM_WAIT(0); } else { VM_WAIT(3); }
    __builtin_amdgcn_s_barrier();
    __builtin_amdgcn_sched_barrier(0);

    if (kt + 2 < NT) {
      int stg = cur + 2; if (stg >= 3) stg -= 3;
      int ko = (kt + 2) * 32;
#pragma unroll
      for (int n = 0; n < 2; ++n) load_lds16(aP[n] + ko, &As[stg][(n * 128 + w * 16) * 32]);
      load_lds16(bP + ko, &Bs[stg][(w * 16) * 32]);
    }

    {
      bf16x8 av[4], bv[4];
      int col = (q ^ (r & 3)) * 8;
#pragma unroll
      for (int i = 0; i < 4; ++i) {
        int row = mb + i * 16 + r;
        av[i] = __builtin_bit_cast(bf16x8, *(const ushort8v*)&As[cur][row * 32 + col]);
      }
#pragma unroll
      for (int j = 0; j < 4; ++j) {
        int row = nb + j * 16 + r;
        bv[j] = __builtin_bit_cast(bf16x8, *(const ushort8v*)&Bs[cur][row * 32 + col]);
      }
      __builtin_amdgcn_s_setprio(1);
#pragma unroll
      for (int i = 0; i < 4; ++i)
#pragma unroll
        for (int j = 0; j < 4; ++j)
          acc[i][j] = __builtin_amdgcn_mfma_f32_16x16x32_bf16(av[i], bv[j], acc[i][j], 0, 0, 0);
      __builtin_amdgcn_s_setprio(0);
    }

    ++cur; if (cur >= 3) cur = 0;
  }

  if constexpr (EPI == 0) {
    // gelu, store bf16 to h1. D: row = q*4+reg, col = r.
#pragma unroll
    for (int i = 0; i < 4; ++i) {
      int mrow = row0 + mb + i * 16 + q * 4;
#pragma unroll
      for (int reg = 0; reg < 4; ++reg) {
        int s = mrow + reg;
        if (s < rend) {
          unsigned short* dst = h1out + (size_t)s * FDIM + nBase + nb + r;
#pragma unroll
          for (int j = 0; j < 4; ++j) {
            float v = acc[i][j][reg];
            float g = 0.5f * v * (1.0f + erff(v * 0.70710678118654752f));
            dst[j * 16] = f2bf(g);
          }
        }
      }
    }
  } else {
    // out[new_index[i]>>1][col] += gate[i]*y (atomic; pair-reduce + K-split)
    const int* order = meta + 256;
#pragma unroll
    for (int i = 0; i < 4; ++i) {
      int mrow = row0 + mb + i * 16 + q * 4;
#pragma unroll
      for (int reg = 0; reg < 4; ++reg) {
        int s = mrow + reg;
        if (s < rend) {
          int itok = order[s];
          float gw = gate[itok];
          int jdx = new_index[itok];
          float* dst = out + (size_t)(jdx >> 1) * HDIM + nBase + nb + r;
#pragma unroll
          for (int j = 0; j < 4; ++j) atomicAdd(dst + j * 16, acc[i][j][reg] * gw);
        }
      }
    }
  }
}

// ===================== Fallback (small workspace): original 128^2 kernels =====================

template <bool PRE>
__global__ __launch_bounds__(256) void gemm1_t(
    const unsigned short* __restrict__ xs, const void* __restrict__ w1v,
    unsigned short* __restrict__ h1, const int* __restrict__ meta) {
  __shared__ unsigned short As[128 * 32];
  __shared__ unsigned short Bs[128 * 32];

  int bx = blockIdx.z;
  if (bx >= meta[24]) return;
  int entry = meta[32 + bx];
  int e = entry >> 16, mt = entry & 0xffff;
  int row0 = meta[8 + e] + mt * 128;
  int rend = meta[8 + e] + meta[e];
  int fBase = blockIdx.x * 128;

  int tid = threadIdx.x;
  int w = tid >> 6, lane = tid & 63;
  int r = lane & 15, q = lane >> 4;
  int wm = (w >> 1) * 64, wn = (w & 1) * 64;

  int ar0 = (w * 16) + (lane >> 2);
  int s0 = min(row0 + ar0, N_TOK - 1);
  int s1 = min(row0 + 64 + ar0, N_TOK - 1);
  const unsigned short* ag0 = xs + (size_t)s0 * HDIM + (lane & 3) * 8;
  const unsigned short* ag1 = xs + (size_t)s1 * HDIM + (lane & 3) * 8;
  unsigned short* al0 = &As[(w * 16) * 32];
  unsigned short* al1 = &As[(64 + w * 16) * 32];

  const float* wbase = nullptr; int brow = 0, bkk = 0;
  brow = tid >> 1; bkk = (tid & 1) * 16;
  wbase = (const float*)w1v + ((size_t)e * FDIM + fBase + brow) * HDIM + bkk;

  floatx4 acc[4][4];
#pragma unroll
  for (int i = 0; i < 4; ++i)
#pragma unroll
    for (int j = 0; j < 4; ++j) acc[i][j] = (floatx4){0.f, 0.f, 0.f, 0.f};

  for (int k0 = 0; k0 < HDIM; k0 += 32) {
    __syncthreads();
    load_lds16(ag0 + k0, al0);
    load_lds16(ag1 + k0, al1);
    {
      const float* gb = wbase + k0;
      float4 f0 = *(const float4*)(gb);
      float4 f1 = *(const float4*)(gb + 4);
      float4 f2 = *(const float4*)(gb + 8);
      float4 f3 = *(const float4*)(gb + 12);
      ushort8v u0, u1;
      u0[0] = f2bf(f0.x); u0[1] = f2bf(f0.y); u0[2] = f2bf(f0.z); u0[3] = f2bf(f0.w);
      u0[4] = f2bf(f1.x); u0[5] = f2bf(f1.y); u0[6] = f2bf(f1.z); u0[7] = f2bf(f1.w);
      u1[0] = f2bf(f2.x); u1[1] = f2bf(f2.y); u1[2] = f2bf(f2.z); u1[3] = f2bf(f2.w);
      u1[4] = f2bf(f3.x); u1[5] = f2bf(f3.y); u1[6] = f2bf(f3.z); u1[7] = f2bf(f3.w);
      *(ushort8v*)&Bs[brow * 32 + bkk] = u0;
      *(ushort8v*)&Bs[brow * 32 + bkk + 8] = u1;
    }
    __syncthreads();

    bf16x8 av[4], bv[4];
#pragma unroll
    for (int i = 0; i < 4; ++i)
      av[i] = __builtin_bit_cast(bf16x8, *(const ushort8v*)&As[(wm + i * 16 + r) * 32 + q * 8]);
#pragma unroll
    for (int j = 0; j < 4; ++j)
      bv[j] = __builtin_bit_cast(bf16x8, *(const ushort8v*)&Bs[(wn + j * 16 + r) * 32 + q * 8]);
#pragma unroll
    for (int i = 0; i < 4; ++i)
#pragma unroll
      for (int j = 0; j < 4; ++j)
        acc[i][j] = __builtin_amdgcn_mfma_f32_16x16x32_bf16(av[i], bv[j], acc[i][j], 0, 0, 0);
  }

#pragma unroll
  for (int i = 0; i < 4; ++i) {
    int mrow = row0 + wm + i * 16 + q * 4;
#pragma unroll
    for (int reg = 0; reg < 4; ++reg) {
      int s = mrow + reg;
      if (s < rend) {
        unsigned short* dst = h1 + (size_t)s * FDIM + fBase + wn + r;
#pragma unroll
        for (int j = 0; j < 4; ++j) {
          float v = acc[i][j][reg];
          float g = 0.5f * v * (1.0f + erff(v * 0.70710678118654752f));
          dst[j * 16] = f2bf(g);
        }
      }
    }
  }
}

template <bool PRE>
__global__ __launch_bounds__(256) void gemm2_t(
    const unsigned short* __restrict__ h1, const void* __restrict__ w2v,
    const float* __restrict__ gate, const int* __restrict__ new_index,
    float* __restrict__ out, const int* __restrict__ meta) {
  __shared__ unsigned short As[128 * 32];
  __shared__ unsigned short Bs[128 * 32];

  int bx = blockIdx.z;
  if (bx >= meta[24]) return;
  int entry = meta[32 + bx];
  int e = entry >> 16, mt = entry & 0xffff;
  int row0 = meta[8 + e] + mt * 128;
  int rend = meta[8 + e] + meta[e];
  int nBase = blockIdx.x * 128;
  int kStart = blockIdx.y * (FDIM / 2);
  int kEnd = kStart + (FDIM / 2);
  const int* order = meta + 256;

  int tid = threadIdx.x;
  int w = tid >> 6, lane = tid & 63;
  int r = lane & 15, q = lane >> 4;
  int wm = (w >> 1) * 64, wn = (w & 1) * 64;

  int ar0 = (w * 16) + (lane >> 2);
  int s0 = min(row0 + ar0, N_TOK - 1);
  int s1 = min(row0 + 64 + ar0, N_TOK - 1);
  const unsigned short* ag0 = h1 + (size_t)s0 * FDIM + (lane & 3) * 8;
  const unsigned short* ag1 = h1 + (size_t)s1 * FDIM + (lane & 3) * 8;
  unsigned short* al0 = &As[(w * 16) * 32];
  unsigned short* al1 = &As[(64 + w * 16) * 32];

  const float* wbase = nullptr; int brow = 0, bkk = 0;
  brow = tid >> 1; bkk = (tid & 1) * 16;
  wbase = (const float*)w2v + ((size_t)e * HDIM + nBase + brow) * FDIM + bkk;

  floatx4 acc[4][4];
#pragma unroll
  for (int i = 0; i < 4; ++i)
#pragma unroll
    for (int j = 0; j < 4; ++j) acc[i][j] = (floatx4){0.f, 0.f, 0.f, 0.f};

  for (int k0 = kStart; k0 < kEnd; k0 += 32) {
    __syncthreads();
    load_lds16(ag0 + k0, al0);
    load_lds16(ag1 + k0, al1);
    {
      const float* gb = wbase + k0;
      float4 f0 = *(const float4*)(gb);
      float4 f1 = *(const float4*)(gb + 4);
      float4 f2 = *(const float4*)(gb + 8);
      float4 f3 = *(const float4*)(gb + 12);
      ushort8v u0, u1;
      u0[0] = f2bf(f0.x); u0[1] = f2bf(f0.y); u0[2] = f2bf(f0.z); u0[3] = f2bf(f0.w);
      u0[4] = f2bf(f1.x); u0[5] = f2bf(f1.y); u0[6] = f2bf(f1.z); u0[7] = f2bf(f1.w);
      u1[0] = f2bf(f2.x); u1[1] = f2bf(f2.y); u1[2] = f2bf(f2.z); u1[3] = f2bf(f2.w);
      u1[4] = f2bf(f3.x); u1[5] = f2bf(f3.y); u1[6] = f2bf(f3.z); u1[7] = f2bf(f3.w);
      *(ushort8v*)&Bs[brow * 32 + bkk] = u0;
      *(ushort8v*)&Bs[brow * 32 + bkk + 8] = u1;
    }
    __syncthreads();

    bf16x8 av[4], bv[4];
#pragma unroll
    for (int i = 0; i < 4; ++i)
      av[i] = __builtin_bit_cast(bf16x8, *(const ushort8v*)&As[(wm + i * 16 + r) * 32 + q * 8]);
#pragma unroll
    for (int j = 0; j < 4; ++j)
      bv[j] = __builtin_bit_cast(bf16x8, *(const ushort8v*)&Bs[(wn + j * 16 + r) * 32 + q * 8]);
#pragma unroll
    for (int i = 0; i < 4; ++i)
#pragma unroll
      for (int j = 0; j < 4; ++j)
        acc[i][j] = __builtin_amdgcn_mfma_f32_16x16x32_bf16(av[i], bv[j], acc[i][j], 0, 0, 0);
  }

#pragma unroll
  for (int i = 0; i < 4; ++i) {
    int mrow = row0 + wm + i * 16 + q * 4;
#pragma unroll
    for (int reg = 0; reg < 4; ++reg) {
      int s = mrow + reg;
      if (s < rend) {
        int itok = order[s];
        float gw = gate[itok];
        int jdx = new_index[itok];
        float* dst = out + (size_t)(jdx >> 1) * HDIM + nBase + wn + r;
#pragma unroll
        for (int j = 0; j < 4; ++j) atomicAdd(dst + j * 16, acc[i][j][reg] * gw);
      }
    }
  }
}

extern "C" void kernel_launch(void* const* d_in, const int* in_sizes, int n_in,
                              void* d_out, int out_size, void* d_ws, size_t ws_size,
                              hipStream_t stream) {
  const float* x        = (const float*)d_in[0];
  const float* gate     = (const float*)d_in[1];
  const int* experts    = (const int*)d_in[2];
  const int* new_index  = (const int*)d_in[3];
  const float* w1       = (const float*)d_in[4];
  const float* w2       = (const float*)d_in[5];
  float* out            = (float*)d_out;

  int* meta = (int*)d_ws;
  int* order = meta + 256;
  const size_t XS_OFF = 65536;
  const size_t XS_SZ  = (size_t)N_TOK * HDIM * 2;          // 16 MB
  const size_t H1_SZ  = (size_t)N_TOK * FDIM * 2;          // 64 MB
  const size_t W_SZ   = (size_t)NEXP * FDIM * HDIM * 2;    // 64 MB each
  unsigned short* xs  = (unsigned short*)((char*)d_ws + XS_OFF);
  unsigned short* h1  = (unsigned short*)((char*)d_ws + XS_OFF + XS_SZ);
  unsigned short* w1b = (unsigned short*)((char*)d_ws + XS_OFF + XS_SZ + H1_SZ);
  unsigned short* w2b = (unsigned short*)((char*)d_ws + XS_OFF + XS_SZ + H1_SZ + W_SZ);
  size_t need_small = XS_OFF + XS_SZ + H1_SZ;
  size_t need_big   = need_small + 2 * W_SZ;
  if (ws_size < need_small) return;
  bool big = ws_size >= need_big;

  hipMemsetAsync(d_out, 0, (size_t)out_size * sizeof(float), stream);
  k_prep<<<1, 1024, 0, stream>>>(experts, meta, order);
  k_pack<<<N_TOK, 256, 0, stream>>>(x, order, xs);

  if (big) {
    int nblk = (int)((size_t)NEXP * FDIM * HDIM / 4 / 256);  // 32768
    k_cvt<<<nblk, 256, 0, stream>>>(w1, w1b);
    k_cvt<<<nblk, 256, 0, stream>>>(w2, w2b);
    // gemm1: M=tokens, N=FDIM (x=32 tiles of 128), K=1024 (NT=32, no K-split)
    gemm_big<HDIM, 32, 0><<<dim3(FDIM / 128, 1, MAXT256), 512, 0, stream>>>(
        xs, w1b, h1, nullptr, nullptr, nullptr, meta);
    // gemm2: M=tokens, N=HDIM (x=8 tiles of 128), K=4096 split 2 (NT=64)
    gemm_big<FDIM, 64, 1><<<dim3(HDIM / 128, 2, MAXT256), 512, 0, stream>>>(
        h1, w2b, nullptr, gate, new_index, out, meta);
  } else {
    gemm1_t<false><<<dim3(FDIM / 128, 1, MAXTILES), 256, 0, stream>>>(xs, w1, h1, meta);
    gemm2_t<false><<<dim3(HDIM / 128, 2, MAXTILES), 256, 0, stream>>>(h1, w2, gate, new_index, out, meta);
  }
}